// Round 11
// baseline (705.449 us; speedup 1.0000x reference)
//
#include <hip/hip_runtime.h>

// MultiHeadElman scan, R11 = R10 with the scan block hand-unrolled:
//  - wx register pipeline (wA0-3 / wB0-3), each value ds_read 4 steps before
//    use -> LDS latency off the chain; static register indexing throughout.
//  - COMPUTE_WX for block n+1 runs BEFORE the last 4 steps of block n, so
//    G3 can prefetch next block's wx rows 0-3 (LDS ops are wave-ordered).
//  - FMA written as fmaf(ror16<k>(hd), rw[k], acc): DPP value in src0 so the
//    backend can fuse v_mov_b32_dpp + v_fmac_f32 -> v_fmac_f32_dpp.
//  - W-x projection per 16-step block: two mfma_f32_16x16x32_f16 (proven R10).
//  - x staged via global_load_lds (unsinkable), drained with counted vmcnt.
// Lane layout (q,g): g0 rows0-15/j-lo, g1 rows16-31/j-hi,
//                    g2 rows0-15/j-hi, g3 rows16-31/j-lo.

typedef __fp16 f16x2 __attribute__((ext_vector_type(2)));
typedef __fp16 f16x8 __attribute__((ext_vector_type(8)));
typedef float  f32x4 __attribute__((ext_vector_type(4)));
typedef unsigned int v2u __attribute__((ext_vector_type(2)));

constexpr int T_STEPS = 4096;
constexpr int B_SZ    = 4;
constexpr int D_SZ    = 2048;
constexpr int H_SZ    = 64;
constexpr int HD      = 32;
constexpr long ST     = (long)B_SZ * D_SZ;   // 8192 floats per t
constexpr int BLK     = 16;                  // steps per block

typedef const __attribute__((address_space(1))) void* gas_t;
typedef __attribute__((address_space(3))) void*       las_t;

// DPP ROW_ROR:N within each 16-lane row (pure VALU).
template<int N>
__device__ __forceinline__ float ror16(float v) {
    if constexpr (N == 0) {
        return v;
    } else {
        return __int_as_float(__builtin_amdgcn_update_dpp(
            __float_as_int(v), __float_as_int(v),
            0x120 + N, 0xF, 0xF, false));
    }
}

__global__ __launch_bounds__(64, 1)
void elman_fused(const float* __restrict__ x,
                 const float* __restrict__ h0,
                 const float* __restrict__ R,
                 const float* __restrict__ Wx,
                 const float* __restrict__ bias,
                 float* __restrict__ out)
{
    const int l = threadIdx.x & 63;
    const int q = l & 15;
    const int g = l >> 4;
    const int joff = (g == 1 || g == 2) ? 16 : 0;
    const int row  = (g & 1) ? 16 + q : q;
    const int h = blockIdx.x & (H_SZ - 1);
    const int b = blockIdx.x >> 6;
    const bool low32 = (l < 32);

    // ---- init-time convention probes (R8/R10-proven) ----
    const int pr = __builtin_amdgcn_update_dpp(l, l, 0x121, 0xF, 0xF, false);
    const bool ror_minus = ((pr & 15) == ((q - 1) & 15));
    const v2u pp = __builtin_amdgcn_permlane16_swap((unsigned)l, (unsigned)l,
                                                    false, false);
    const bool sel_x = (pp.x == (unsigned)(l ^ 16));

    // ---- R row slice, pre-permuted for the probed rotation direction ----
    float rw[16];
    {
        const float* Rrow = R + (h * HD + row) * HD + joff;
        if (ror_minus) {
#pragma unroll
            for (int k = 0; k < 16; ++k) rw[k] = Rrow[(q - k) & 15];
        } else {
#pragma unroll
            for (int k = 0; k < 16; ++k) rw[k] = Rrow[(q + k) & 15];
        }
    }

    // ---- MFMA B fragments: B[k][n] = Wx[h][n][k] (f16), loaded once ----
    union AF { f16x8 v; f16x2 p[4]; };
    AF bf0, bf1;
    {
        const int n  = l & 15;
        const int k0 = (l >> 4) * 8;
        const float4* wp0 = (const float4*)(Wx + (h * HD + n) * HD + k0);
        const float4* wp1 = (const float4*)(Wx + (h * HD + n + 16) * HD + k0);
        float4 u = wp0[0], v = wp0[1];
        bf0.p[0] = __builtin_amdgcn_cvt_pkrtz(u.x, u.y);
        bf0.p[1] = __builtin_amdgcn_cvt_pkrtz(u.z, u.w);
        bf0.p[2] = __builtin_amdgcn_cvt_pkrtz(v.x, v.y);
        bf0.p[3] = __builtin_amdgcn_cvt_pkrtz(v.z, v.w);
        u = wp1[0]; v = wp1[1];
        bf1.p[0] = __builtin_amdgcn_cvt_pkrtz(u.x, u.y);
        bf1.p[1] = __builtin_amdgcn_cvt_pkrtz(u.z, u.w);
        bf1.p[2] = __builtin_amdgcn_cvt_pkrtz(v.x, v.y);
        bf1.p[3] = __builtin_amdgcn_cvt_pkrtz(v.z, v.w);
    }
    const float bn0 = bias[h * HD + (l & 15)];
    const float bn1 = bias[h * HD + (l & 15) + 16];

    float hn = h0[(b * H_SZ + h) * HD + row];

    __shared__ __align__(16) float xl[2][512];   // x tiles, gl_lds linear
    __shared__ float wxl[2][BLK][32];            // wx tiles

    // A-frag LDS word offsets (R10-proven)
    const int m  = l & 15;
    const int J0 = (l >> 4) * 2, J1 = J0 + 1;
    const int aw0 = 64 * (J0 & 3) + 4 * m + 256 * (J0 >> 2);
    const int aw1 = 64 * (J1 & 3) + 4 * m + 256 * (J1 >> 2);

    const float* gx0 = x + (long)(l & 15) * ST + (long)b * D_SZ + h * HD
                         + (l >> 4) * 4;
    const float* gx1 = gx0 + 16;

    float* op = out + (long)b * D_SZ + h * HD + row;

#define STAGE(nbuf, t0) do {                                                  \
        __builtin_amdgcn_global_load_lds((gas_t)(gx0 + (long)(t0) * ST),      \
                                         (las_t)&xl[nbuf][0],   16, 0, 0);    \
        __builtin_amdgcn_global_load_lds((gas_t)(gx1 + (long)(t0) * ST),      \
                                         (las_t)&xl[nbuf][256], 16, 0, 0);    \
    } while (0)

#define COMPUTE_WX(nbuf) do {                                                 \
        float4 xa = *(const float4*)&xl[nbuf][aw0];                           \
        float4 xc = *(const float4*)&xl[nbuf][aw1];                           \
        AF af;                                                                \
        af.p[0] = __builtin_amdgcn_cvt_pkrtz(xa.x, xa.y);                     \
        af.p[1] = __builtin_amdgcn_cvt_pkrtz(xa.z, xa.w);                     \
        af.p[2] = __builtin_amdgcn_cvt_pkrtz(xc.x, xc.y);                     \
        af.p[3] = __builtin_amdgcn_cvt_pkrtz(xc.z, xc.w);                     \
        f32x4 c0 = {bn0, bn0, bn0, bn0};                                      \
        f32x4 c1 = {bn1, bn1, bn1, bn1};                                      \
        c0 = __builtin_amdgcn_mfma_f32_16x16x32_f16(af.v, bf0.v, c0, 0, 0, 0);\
        c1 = __builtin_amdgcn_mfma_f32_16x16x32_f16(af.v, bf1.v, c1, 0, 0, 0);\
        const int mr = (l >> 4) * 4, nc = l & 15;                             \
        wxl[nbuf][mr + 0][nc] = c0[0]; wxl[nbuf][mr + 0][nc + 16] = c1[0];    \
        wxl[nbuf][mr + 1][nc] = c0[1]; wxl[nbuf][mr + 1][nc + 16] = c1[1];    \
        wxl[nbuf][mr + 2][nc] = c0[2]; wxl[nbuf][mr + 2][nc + 16] = c1[2];    \
        wxl[nbuf][mr + 3][nc] = c0[3]; wxl[nbuf][mr + 3][nc + 16] = c1[3];    \
    } while (0)

// one scan step; WX = this step's wx (register); LOAD = wx prefetch stmt
#define STEP(WX, LOAD) do {                                                   \
        const v2u hp_ = __builtin_amdgcn_permlane16_swap(                     \
            __float_as_uint(hn), __float_as_uint(hn), false, false);          \
        const float f16_ = __uint_as_float(sel_x ? hp_.x : hp_.y);            \
        const float hd = low32 ? hn : f16_;                                   \
        float r0 = ror16<0>(hd) * rw[0];                                      \
        float r1 = ror16<1>(hd) * rw[1];                                      \
        float r2 = ror16<2>(hd) * rw[2];                                      \
        float r3 = ror16<3>(hd) * rw[3];                                      \
        LOAD;                                                                 \
        r0 = fmaf(ror16<4>(hd),  rw[4],  r0);                                 \
        r1 = fmaf(ror16<5>(hd),  rw[5],  r1);                                 \
        r2 = fmaf(ror16<6>(hd),  rw[6],  r2);                                 \
        r3 = fmaf(ror16<7>(hd),  rw[7],  r3);                                 \
        r0 = fmaf(ror16<8>(hd),  rw[8],  r0);                                 \
        r1 = fmaf(ror16<9>(hd),  rw[9],  r1);                                 \
        r2 = fmaf(ror16<10>(hd), rw[10], r2);                                 \
        r3 = fmaf(ror16<11>(hd), rw[11], r3);                                 \
        r0 = fmaf(ror16<12>(hd), rw[12], r0);                                 \
        r1 = fmaf(ror16<13>(hd), rw[13], r1);                                 \
        r2 = fmaf(ror16<14>(hd), rw[14], r2);                                 \
        r3 = fmaf(ror16<15>(hd), rw[15], r3);                                 \
        const float s_ = (r0 + r1) + (r2 + r3);                               \
        const v2u sp_ = __builtin_amdgcn_permlane32_swap(                     \
            __float_as_uint(s_), __float_as_uint(s_), false, false);          \
        const float pre_ = (__uint_as_float(sp_.x) + __uint_as_float(sp_.y))  \
                         + (WX);                                              \
        hn = pre_ * __builtin_amdgcn_rcpf(1.0f + __builtin_fabsf(pre_));      \
        op[0] = hn;                                                           \
        op += ST;                                                             \
    } while (0)

    // ---- prologue: block 0 ----
    STAGE(0, 0);
    asm volatile("s_waitcnt vmcnt(0)" ::: "memory");
    COMPUTE_WX(0);
    float wA0 = wxl[0][0][row], wA1 = wxl[0][1][row];
    float wA2 = wxl[0][2][row], wA3 = wxl[0][3][row];
    float wB0, wB1, wB2, wB3;

    for (int tb = 0; tb < T_STEPS; tb += BLK) {
        const int cur = (tb >> 4) & 1, nxt = cur ^ 1;
        const bool more = (tb + BLK) < T_STEPS;
        if (more) STAGE(nxt, tb + BLK);       // unsinkable gl_lds

        // G0: steps 0-3 (wA), prefetch rows 4-7 -> wB
        STEP(wA0, wB0 = wxl[cur][4][row]);
        STEP(wA1, wB1 = wxl[cur][5][row]);
        STEP(wA2, wB2 = wxl[cur][6][row]);
        STEP(wA3, wB3 = wxl[cur][7][row]);
        // G1: steps 4-7 (wB), prefetch rows 8-11 -> wA
        STEP(wB0, wA0 = wxl[cur][8][row]);
        STEP(wB1, wA1 = wxl[cur][9][row]);
        STEP(wB2, wA2 = wxl[cur][10][row]);
        STEP(wB3, wA3 = wxl[cur][11][row]);
        // G2: steps 8-11 (wA), prefetch rows 12-15 -> wB
        STEP(wA0, wB0 = wxl[cur][12][row]);
        STEP(wA1, wB1 = wxl[cur][13][row]);
        STEP(wA2, wB2 = wxl[cur][14][row]);
        STEP(wA3, wB3 = wxl[cur][15][row]);

        // next block's wx: x resident once the 2 gl_lds drain.
        // queue: [4 prev stores][2 gl_lds][12 stores] -> vmcnt(12) = glds done
        if (more) {
            asm volatile("s_waitcnt vmcnt(12)" ::: "memory");
            COMPUTE_WX(nxt);
        }

        // G3: steps 12-15 (wB), prefetch next block rows 0-3 -> wA
        // (if !more these reads return stale data, unused; in-bounds)
        STEP(wB0, wA0 = wxl[nxt][0][row]);
        STEP(wB1, wA1 = wxl[nxt][1][row]);
        STEP(wB2, wA2 = wxl[nxt][2][row]);
        STEP(wB3, wA3 = wxl[nxt][3][row]);
    }

    out[(long)T_STEPS * ST + (b * H_SZ + h) * HD + row] = hn;
#undef STEP
#undef STAGE
#undef COMPUTE_WX
}

extern "C" void kernel_launch(void* const* d_in, const int* in_sizes, int n_in,
                              void* d_out, int out_size, void* d_ws, size_t ws_size,
                              hipStream_t stream) {
    const float* x    = (const float*)d_in[0];
    const float* h0   = (const float*)d_in[1];
    const float* R    = (const float*)d_in[2];
    const float* Wx   = (const float*)d_in[3];
    const float* bias = (const float*)d_in[4];
    float* out = (float*)d_out;

    elman_fused<<<dim3(B_SZ * H_SZ), dim3(64), 0, stream>>>(x, h0, R, Wx, bias, out);
}

// Round 12
// 580.396 us; speedup vs baseline: 1.2155x; 1.2155x over previous
//
#include <hip/hip_runtime.h>

// MultiHeadElman scan, R12: op-count-minimized step via packed-f16 dot.
// Confirmed R10/R11: a solo wave sustains ~4.6 cy/instr, so step time ~
// op_count x 4.6. R12 halves the op count:
//  - h packed as f16 pairs; period-8 replication per 16-lane DPP row ->
//    7x row_ror (vs 15) delivers all pair rotations.
//  - 8x v_dot2_f32_f16 (f32 accumulate) replace 16 FMAs.
//  - natural row layout (row = l&31, half p = l>>5): permlane16 fix GONE.
//  - repack: 2x ds_bpermute (lanes 16p+2m, +1) + 1 cvt_pkrtz.
//  - wx pre-halved (W,bias scaled 0.5 at init) and folded into acc init;
//    pre = u+v via permlane32_swap (R8-proven convention-invariant).
//  - W-x via two mfma_f32_16x16x32_f16 per 16-step block (R10-proven),
//    x staged by global_load_lds, drained with counted vmcnt (R10-proven).
//  - scan loop ROLLED (R10 beat R11's unroll).

typedef __fp16 f16x2 __attribute__((ext_vector_type(2)));
typedef __fp16 f16x8 __attribute__((ext_vector_type(8)));
typedef float  f32x4 __attribute__((ext_vector_type(4)));
typedef unsigned int v2u __attribute__((ext_vector_type(2)));

constexpr int T_STEPS = 4096;
constexpr int B_SZ    = 4;
constexpr int D_SZ    = 2048;
constexpr int H_SZ    = 64;
constexpr int HD      = 32;
constexpr long ST     = (long)B_SZ * D_SZ;   // 8192 floats per t
constexpr int BLK     = 16;                  // steps per block

typedef const __attribute__((address_space(1))) void* gas_t;
typedef __attribute__((address_space(3))) void*       las_t;

#if __has_builtin(__builtin_amdgcn_fdot2)
__device__ __forceinline__ float FDOT2(f16x2 a, f16x2 b, float c) {
    return __builtin_amdgcn_fdot2(a, b, c, false);
}
#else
__device__ __forceinline__ float FDOT2(f16x2 a, f16x2 b, float c) {
    return fmaf((float)a.x, (float)b.x, fmaf((float)a.y, (float)b.y, c));
}
#endif

// DPP ROW_ROR:N of a 32-bit reg holding an f16 pair.
template<int N>
__device__ __forceinline__ f16x2 rorpair(unsigned u) {
    const unsigned r = (unsigned)__builtin_amdgcn_update_dpp(
        (int)u, (int)u, 0x120 + N, 0xF, 0xF, false);
    return __builtin_bit_cast(f16x2, r);
}

__global__ __launch_bounds__(64, 1)
void elman_fused(const float* __restrict__ x,
                 const float* __restrict__ h0,
                 const float* __restrict__ R,
                 const float* __restrict__ Wx,
                 const float* __restrict__ bias,
                 float* __restrict__ out)
{
    const int l = threadIdx.x & 63;
    const int row = l & 31;              // output row this lane owns
    const int p   = l >> 5;              // j-half this lane covers
    const int m0  = l & 7;               // home pair index
    const int h = blockIdx.x & (H_SZ - 1);
    const int b = blockIdx.x >> 6;

    // ---- DPP direction probe (R8-proven) ----
    const int q16 = l & 15;
    const int pr = __builtin_amdgcn_update_dpp(l, l, 0x121, 0xF, 0xF, false);
    const bool ror_minus = ((pr & 15) == ((q16 - 1) & 15));

    // ---- R weights as f16 pairs, rotation-ordered ----
    f16x2 rw2[8];
    {
        const float* Rrow = R + (h * HD + row) * HD + 16 * p;
#pragma unroll
        for (int k = 0; k < 8; ++k) {
            const int m = ror_minus ? ((m0 - k) & 7) : ((m0 + k) & 7);
            rw2[k] = __builtin_amdgcn_cvt_pkrtz(Rrow[2 * m], Rrow[2 * m + 1]);
        }
    }

    // ---- MFMA B fragments: B[k][n] = 0.5*Wx[h][n][k] (f16), loaded once ----
    // (wx pre-halved so each j-half's accumulator carries wx/2; u+v restores)
    union AF { f16x8 v; f16x2 pcs[4]; };
    AF bf0, bf1;
    {
        const int n  = l & 15;
        const int k0 = (l >> 4) * 8;
        const float4* wp0 = (const float4*)(Wx + (h * HD + n) * HD + k0);
        const float4* wp1 = (const float4*)(Wx + (h * HD + n + 16) * HD + k0);
        float4 u = wp0[0], v = wp0[1];
        bf0.pcs[0] = __builtin_amdgcn_cvt_pkrtz(0.5f * u.x, 0.5f * u.y);
        bf0.pcs[1] = __builtin_amdgcn_cvt_pkrtz(0.5f * u.z, 0.5f * u.w);
        bf0.pcs[2] = __builtin_amdgcn_cvt_pkrtz(0.5f * v.x, 0.5f * v.y);
        bf0.pcs[3] = __builtin_amdgcn_cvt_pkrtz(0.5f * v.z, 0.5f * v.w);
        u = wp1[0]; v = wp1[1];
        bf1.pcs[0] = __builtin_amdgcn_cvt_pkrtz(0.5f * u.x, 0.5f * u.y);
        bf1.pcs[1] = __builtin_amdgcn_cvt_pkrtz(0.5f * u.z, 0.5f * u.w);
        bf1.pcs[2] = __builtin_amdgcn_cvt_pkrtz(0.5f * v.x, 0.5f * v.y);
        bf1.pcs[3] = __builtin_amdgcn_cvt_pkrtz(0.5f * v.z, 0.5f * v.w);
    }
    const float bn0 = 0.5f * bias[h * HD + (l & 15)];
    const float bn1 = 0.5f * bias[h * HD + (l & 15) + 16];

    float hn = h0[(b * H_SZ + h) * HD + row];

    __shared__ __align__(16) float xl[2][512];     // x tiles, gl_lds linear
    __shared__ float wxl[2][BLK + 2][32];          // wx/2 tiles (+2 pad rows)

    // A-frag LDS word offsets (R10-proven)
    const int J0 = (l >> 4) * 2, J1 = J0 + 1;
    const int aw0 = 64 * (J0 & 3) + 4 * (l & 15) + 256 * (J0 >> 2);
    const int aw1 = 64 * (J1 & 3) + 4 * (l & 15) + 256 * (J1 >> 2);

    const float* gx0 = x + (long)(l & 15) * ST + (long)b * D_SZ + h * HD
                         + (l >> 4) * 4;
    const float* gx1 = gx0 + 16;

    float* op = out + (long)b * D_SZ + h * HD + row;

    // bpermute byte addrs for the pair repack: h[16p+2m0], h[16p+2m0+1]
    const int ba0 = (16 * p + 2 * m0) * 4;
    const int ba1 = ba0 + 4;

#define STAGE(nbuf, t0) do {                                                  \
        __builtin_amdgcn_global_load_lds((gas_t)(gx0 + (long)(t0) * ST),      \
                                         (las_t)&xl[nbuf][0],   16, 0, 0);    \
        __builtin_amdgcn_global_load_lds((gas_t)(gx1 + (long)(t0) * ST),      \
                                         (las_t)&xl[nbuf][256], 16, 0, 0);    \
    } while (0)

#define COMPUTE_WX(nbuf) do {                                                 \
        float4 xa = *(const float4*)&xl[nbuf][aw0];                           \
        float4 xc = *(const float4*)&xl[nbuf][aw1];                           \
        AF af;                                                                \
        af.pcs[0] = __builtin_amdgcn_cvt_pkrtz(xa.x, xa.y);                   \
        af.pcs[1] = __builtin_amdgcn_cvt_pkrtz(xa.z, xa.w);                   \
        af.pcs[2] = __builtin_amdgcn_cvt_pkrtz(xc.x, xc.y);                   \
        af.pcs[3] = __builtin_amdgcn_cvt_pkrtz(xc.z, xc.w);                   \
        f32x4 c0 = {bn0, bn0, bn0, bn0};                                      \
        f32x4 c1 = {bn1, bn1, bn1, bn1};                                      \
        c0 = __builtin_amdgcn_mfma_f32_16x16x32_f16(af.v, bf0.v, c0, 0, 0, 0);\
        c1 = __builtin_amdgcn_mfma_f32_16x16x32_f16(af.v, bf1.v, c1, 0, 0, 0);\
        const int mr = (l >> 4) * 4, nc = l & 15;                             \
        wxl[nbuf][mr + 0][nc] = c0[0]; wxl[nbuf][mr + 0][nc + 16] = c1[0];    \
        wxl[nbuf][mr + 1][nc] = c0[1]; wxl[nbuf][mr + 1][nc + 16] = c1[1];    \
        wxl[nbuf][mr + 2][nc] = c0[2]; wxl[nbuf][mr + 2][nc + 16] = c1[2];    \
        wxl[nbuf][mr + 3][nc] = c0[3]; wxl[nbuf][mr + 3][nc + 16] = c1[3];    \
    } while (0)

    // ---- prologue: block 0 ----
    STAGE(0, 0);
    asm volatile("s_waitcnt vmcnt(0)" ::: "memory");
    COMPUTE_WX(0);
    float wx0 = wxl[0][0][row];    // this step's wx/2
    float wx1 = wxl[0][1][row];    // next step's wx/2

    for (int tb = 0; tb < T_STEPS; tb += BLK) {
        const int cur = (tb >> 4) & 1, nxt = cur ^ 1;
        const bool more = (tb + BLK) < T_STEPS;
        if (more) STAGE(nxt, tb + BLK);      // unsinkable gl_lds

#pragma clang loop unroll(disable)
        for (int k = 0; k < BLK; ++k) {
            const float wxn = wxl[cur][k + 2][row];   // 2-ahead (pad rows)

            // repack h -> f16 pair (2 bpermute + 1 cvt; only chain LDS ops)
            const int hni = __float_as_int(hn);
            const float he = __int_as_float(
                __builtin_amdgcn_ds_bpermute(ba0, hni));
            const float ho = __int_as_float(
                __builtin_amdgcn_ds_bpermute(ba1, hni));
            const f16x2 pd = __builtin_amdgcn_cvt_pkrtz(he, ho);
            const unsigned pdu = __builtin_bit_cast(unsigned, pd);

            // 16 products = 8 fdot2; pair rotations via 7 DPP (period-8)
            float a0 = FDOT2(pd,            rw2[0], wx0);   // wx/2 folded in
            float a1 = FDOT2(rorpair<1>(pdu), rw2[1], 0.0f);
            a0 = FDOT2(rorpair<2>(pdu), rw2[2], a0);
            a1 = FDOT2(rorpair<3>(pdu), rw2[3], a1);
            a0 = FDOT2(rorpair<4>(pdu), rw2[4], a0);
            a1 = FDOT2(rorpair<5>(pdu), rw2[5], a1);
            a0 = FDOT2(rorpair<6>(pdu), rw2[6], a0);
            a1 = FDOT2(rorpair<7>(pdu), rw2[7], a1);
            const float s = a0 + a1;

            // half-combine (R8-proven): {x,y} = {own, partner} either way
            const v2u sp = __builtin_amdgcn_permlane32_swap(
                __float_as_uint(s), __float_as_uint(s), false, false);
            const float pre = __uint_as_float(sp.x) + __uint_as_float(sp.y);

            // softsign
            hn = pre * __builtin_amdgcn_rcpf(1.0f + __builtin_fabsf(pre));

            op[0] = hn;          // dup lanes: same value, same address
            op += ST;
            wx0 = wx1; wx1 = wxn;
        }

        if (more) {
            // queue: [2 gl_lds][16 stores] -> vmcnt(16) = gl_lds drained
            asm volatile("s_waitcnt vmcnt(16)" ::: "memory");
            COMPUTE_WX(nxt);
            wx0 = wxl[nxt][0][row];
            wx1 = wxl[nxt][1][row];
        }
    }

    out[(long)T_STEPS * ST + (b * H_SZ + h) * HD + row] = hn;
#undef STAGE
#undef COMPUTE_WX
}

extern "C" void kernel_launch(void* const* d_in, const int* in_sizes, int n_in,
                              void* d_out, int out_size, void* d_ws, size_t ws_size,
                              hipStream_t stream) {
    const float* x    = (const float*)d_in[0];
    const float* h0   = (const float*)d_in[1];
    const float* R    = (const float*)d_in[2];
    const float* Wx   = (const float*)d_in[3];
    const float* bias = (const float*)d_in[4];
    float* out = (float*)d_out;

    elman_fused<<<dim3(B_SZ * H_SZ), dim3(64), 0, stream>>>(x, h0, R, Wx, bias, out);
}